// Round 8
// baseline (122.798 us; speedup 1.0000x reference)
//
#include <hip/hip_runtime.h>

// SoftDtwRkdDistance: B=32, T=96, D=128, f32 in, scalar f32 out.
// Fused design: one 256-thread block per (unique pair, tensor).
//   Phase C (4 waves): LDS-staged 6x6 register-tile GEMM (round-4 proven),
//     C' = (xn_a+xn_b-2*dot)*rg2 written into LDS in ANTI-DIAGONAL-MAJOR
//     layout (rg2 = -log2e/gamma).
//   Phase DP (wave 0): 191-diagonal recurrence in registers; z''-domain
//     exp2 softmin, 2 shfls/diag via shadow regs, 4-deep LDS prefetch queue.
//   DP of finished blocks overlaps C-phase of other resident blocks.
// K0 xn: row squared-norms.  K3 reduce: means + smooth-L1.

constexpr int TT = 96;
constexpr int DD = 128;
constexpr int BB = 32;
constexpr int NP = BB * BB;               // 1024
constexpr int NPAIR = BB * (BB + 1) / 2;  // 528
constexpr int CSZ = TT * TT;              // 9216 floats
constexpr float FINF = 1e10f;
constexpr float LOG2E = 1.4426950408889634f;
constexpr float LN2 = 0.6931471805599453f;

__device__ __forceinline__ int tri_base(int a) {   // pairs with first index < a
  return a * BB - (a * (a - 1)) / 2;
}
__device__ __forceinline__ void tri_decode(int pr, int& a, int& b) {
  a = (int)((65.0f - sqrtf(4225.0f - 8.0f * (float)pr)) * 0.5f);
  while (tri_base(a + 1) <= pr) ++a;
  while (tri_base(a) > pr) --a;
  b = a + (pr - tri_base(a));
}
__device__ __forceinline__ int diag_base(int d) {
  return (d <= 95) ? ((d * (d + 1)) >> 1)
                   : 4656 + (((d - 96) * (287 - d)) >> 1);
}
// softmin in z''-domain, op order matches reference (up, left, diag)
__device__ __forceinline__ float smin2(float u, float lf, float dg) {
  float m = fmaxf(fmaxf(u, lf), dg);
  float s = __builtin_amdgcn_exp2f(u - m) + __builtin_amdgcn_exp2f(lf - m)
          + __builtin_amdgcn_exp2f(dg - m);
  return m + __builtin_amdgcn_logf(s);
}

// K0: row squared-norms xn[2][BB*TT]
__global__ void xn_kernel(const float* __restrict__ xs,
                          const float* __restrict__ xt,
                          float* __restrict__ xn) {
  int idx = blockIdx.x * 256 + threadIdx.x;
  if (idx >= 2 * BB * TT) return;
  int which = idx / (BB * TT);
  int row = idx - which * (BB * TT);
  const float* x = which ? xt : xs;
  const float4* xv = reinterpret_cast<const float4*>(x + (size_t)row * DD);
  float acc = 0.f;
#pragma unroll
  for (int k = 0; k < DD / 4; ++k) {
    float4 v = xv[k];
    acc = fmaf(v.x, v.x, acc);
    acc = fmaf(v.y, v.y, acc);
    acc = fmaf(v.z, v.z, acc);
    acc = fmaf(v.w, v.w, acc);
  }
  xn[idx] = acc;
}

// DP step macros (proven 4-deep version, cb -> LDS diag-major buffer)
#define STEP_RISE(d, qa, qb) do {                                        \
    float cA = qa, cB = qb;                                              \
    int dn = (d) + 4;                                                    \
    if (dn <= 190) {                                                     \
      int nb = diag_base(dn);                                            \
      qa = cbp[nb + l]; qb = cbp[nb + 64 + l];                           \
    }                                                                    \
    float rA1 = __shfl(A1, lm1), rB1 = __shfl(B1, lm1);                  \
    float upA = l0 ? NEGI : rA1;                                         \
    float dgA = l0 ? NEGI : pA1;                                         \
    float upB = l0 ? rA1 : rB1;                                          \
    float dgB = l0 ? pA1 : pB1;                                          \
    float nA = cA + smin2(upA, A1, dgA);                                 \
    float nB = cB + smin2(upB, B1, dgB);                                 \
    A2 = A1; B2 = B1;                                                    \
    A1 = (l < (d) + 1) ? nA : NEGI;                                      \
    B1 = (64 + l < (d) + 1) ? nB : NEGI;                                 \
    pA1 = rA1; pB1 = rB1;                                                \
  } while (0)

#define STEP_FALL(d, qa, qb) do {                                        \
    float cA = qa, cB = qb;                                              \
    int dn = (d) + 4;                                                    \
    if (dn <= 190) {                                                     \
      int nb = diag_base(dn);                                            \
      qa = cbp[nb + l]; qb = cbp[nb + 64 + l];                           \
    }                                                                    \
    float rA1 = __shfl(A1, lp1), rB1 = __shfl(B1, lp1);                  \
    float lfA = l63 ? rB1 : rA1;                                         \
    float lfB = rB1;                                                     \
    float dgA = l63 ? pB1 : pA1;                                         \
    float dgB = pB1;                                                     \
    float nA = cA + smin2(A1, lfA, dgA);                                 \
    float nB = cB + smin2(B1, lfB, dgB);                                 \
    A2 = A1; B2 = B1;                                                    \
    int len = 191 - (d);                                                 \
    A1 = (l < len) ? nA : NEGI;                                          \
    B1 = (64 + l < len) ? nB : NEGI;                                     \
    pA1 = rA1; pB1 = rB1;                                                \
  } while (0)

// K1 fused: C in LDS (diag-major) then register DP on wave 0.
__global__ __launch_bounds__(256)
void sdtw_kernel(const float* __restrict__ xs,
                 const float* __restrict__ xt,
                 const float* __restrict__ xn,    // [2][BB*TT]
                 const float* __restrict__ gptr,
                 float* __restrict__ dtw) {       // [2][NP]
  __shared__ __align__(16) float Cs[CSZ];     // diag-major C''; staging aliases front
  __shared__ float xna[TT];
  __shared__ float xnb[TT];

  const int pr = blockIdx.x;
  int a, b;
  tri_decode(pr, a, b);
  const int w = blockIdx.y;
  const float* x = w ? xt : xs;
  const float* xnw = xn + w * (BB * TT);
  const float* xa = x + (size_t)a * TT * DD;
  const float* xb = x + (size_t)b * TT * DD;
  const int tid = threadIdx.x;

  if (tid < TT) {
    xna[tid] = xnw[a * TT + tid];
    xnb[tid] = xnw[b * TT + tid];
  }

  constexpr int SROW = 36;                 // staged row stride (floats), 16B-aligned
  float* xa_s = Cs;                        // [96][36] = 3456 floats
  float* xb_s = Cs + TT * SROW;            // 6912 <= 9216 floats total

  // lane remap: each 16-lane quarter spans 8 tx x 2 ty -> av4/bv4 <=2-way
  const int wv = tid >> 6;
  const int lane = tid & 63;
  const int tx = (lane & 7) + (wv & 1) * 8;      // 0..15
  const int ty = (lane >> 3) + (wv >> 1) * 8;    // 0..15
  const int t0 = ty * 6, s0 = tx * 6;

  float acc[6][6];
#pragma unroll
  for (int r = 0; r < 6; ++r)
#pragma unroll
    for (int c = 0; c < 6; ++c) acc[r][c] = 0.f;

  for (int d0 = 0; d0 < DD; d0 += 32) {
    __syncthreads();   // previous chunk's reads done before overwrite
    const float4* ga = reinterpret_cast<const float4*>(xa + d0);
    const float4* gb = reinterpret_cast<const float4*>(xb + d0);
    float4* sa = reinterpret_cast<float4*>(xa_s);
    float4* sb = reinterpret_cast<float4*>(xb_s);
#pragma unroll
    for (int it = 0; it < 3; ++it) {
      int idx = tid + it * 256;            // 0..767 float4s (96 rows x 8)
      int t = idx >> 3, k4 = idx & 7;
      sa[t * (SROW / 4) + k4] = ga[t * (DD / 4) + k4];
      sb[t * (SROW / 4) + k4] = gb[t * (DD / 4) + k4];
    }
    __syncthreads();
#pragma unroll
    for (int k4 = 0; k4 < 8; ++k4) {
      float4 av4[6], bv4[6];
#pragma unroll
      for (int r = 0; r < 6; ++r)
        av4[r] = reinterpret_cast<const float4*>(xa_s + (t0 + r) * SROW)[k4];
#pragma unroll
      for (int c = 0; c < 6; ++c)
        bv4[c] = reinterpret_cast<const float4*>(xb_s + (s0 + c) * SROW)[k4];
#pragma unroll
      for (int r = 0; r < 6; ++r)
#pragma unroll
        for (int c = 0; c < 6; ++c) {
          acc[r][c] = fmaf(av4[r].x, bv4[c].x, acc[r][c]);
          acc[r][c] = fmaf(av4[r].y, bv4[c].y, acc[r][c]);
          acc[r][c] = fmaf(av4[r].z, bv4[c].z, acc[r][c]);
          acc[r][c] = fmaf(av4[r].w, bv4[c].w, acc[r][c]);
        }
    }
  }
  __syncthreads();   // staging reads complete; safe to overwrite with diag-major C''
  const float gamma = gptr[0];
  const float rg2 = -LOG2E / gamma;
#pragma unroll
  for (int r = 0; r < 6; ++r) {
    const int i = t0 + r;
    float xr = xna[i];
#pragma unroll
    for (int c = 0; c < 6; ++c) {
      const int j = s0 + c;
      float cv = xr + xnb[j] - 2.0f * acc[r][c];   // exact ref C
      const int d = i + j;
      const int pos = (d <= 95) ? i : i - (d - 95);
      Cs[diag_base(d) + pos] = cv * rg2;           // pre-scaled, diag-major
    }
  }
  __syncthreads();
  if (tid >= 64) return;   // waves 1..3 done; wave 0 runs the DP

  const float NEGI = FINF * rg2;          // invalid cell in z''-domain
  const float* cbp = Cs;
  const int l = lane;
  const int lp1 = (l + 1) & 63, lm1 = (l + 63) & 63;
  const bool l0 = (l == 0), l63 = (l == 63);

  // prefetch queue: preload diagonals 1..4
  float q0A, q0B, q1A, q1B, q2A, q2B, q3A, q3B;
  {
    int b1 = diag_base(1), b2 = diag_base(2), b3 = diag_base(3), b4 = diag_base(4);
    q0A = cbp[b1 + l]; q0B = cbp[b1 + 64 + l];
    q1A = cbp[b2 + l]; q1B = cbp[b2 + 64 + l];
    q2A = cbp[b3 + l]; q2B = cbp[b3 + 64 + l];
    q3A = cbp[b4 + l]; q3B = cbp[b4 + 64 + l];
  }

  // d=0 peel: r(0,0)'' = C''(0,0)
  float A1 = l0 ? cbp[0] : NEGI;
  float B1 = NEGI, A2 = NEGI, B2 = NEGI;
  float pA1 = NEGI, pB1 = NEGI;   // shadow: last iter's shfl(A1/B1)

  // rising: d = 1..92 in groups of 4, then peel 93,94,95
  for (int g = 0; g < 23; ++g) {
    int d = 1 + g * 4;
    STEP_RISE(d,     q0A, q0B);
    STEP_RISE(d + 1, q1A, q1B);
    STEP_RISE(d + 2, q2A, q2B);
    STEP_RISE(d + 3, q3A, q3B);
  }
  STEP_RISE(93, q0A, q0B);
  STEP_RISE(94, q1A, q1B);
  STEP_RISE(95, q2A, q2B);

  // d = 96 boundary: offsets (0, +1, 0); consumes q3, prefetches 100
  {
    float cA = q3A, cB = q3B;
    int nb = diag_base(100);
    q3A = cbp[nb + l]; q3B = cbp[nb + 64 + l];
    float rA1 = __shfl(A1, lp1), rB1 = __shfl(B1, lp1);
    float lfA = l63 ? rB1 : rA1;
    float lfB = rB1;
    float nA = cA + smin2(A1, lfA, A2);
    float nB = cB + smin2(B1, lfB, B2);
    A2 = A1; B2 = B1;
    A1 = (l < 95) ? nA : NEGI;          // len = 95
    B1 = (64 + l < 95) ? nB : NEGI;
    pA1 = rA1; pB1 = rB1;
  }

  // falling: d = 97..188 in groups of 4, then peel 189, 190
  for (int g = 0; g < 23; ++g) {
    int d = 97 + g * 4;
    STEP_FALL(d,     q0A, q0B);
    STEP_FALL(d + 1, q1A, q1B);
    STEP_FALL(d + 2, q2A, q2B);
    STEP_FALL(d + 3, q3A, q3B);
  }
  STEP_FALL(189, q0A, q0B);
  STEP_FALL(190, q1A, q1B);

  // cell (95,95) = position 0 of diag 190 -> lane 0, A1
  if (l0) {
    float v = A1 * (-gamma * LN2);       // back to r-domain
    dtw[w * NP + a * BB + b] = v;
    dtw[w * NP + b * BB + a] = v;        // bit-exact by transpose symmetry
  }
}

// K3: means + normalized smooth-L1 (single block).
__global__ void reduce_kernel(const float* __restrict__ dtw,
                              float* __restrict__ out) {
  __shared__ double sh[256];
  const int tid = threadIdx.x;
  double ss = 0, st = 0;
  for (int k = tid; k < NP; k += 256) {
    ss += (double)dtw[k];
    st += (double)dtw[NP + k];
  }
  sh[tid] = ss; __syncthreads();
  for (int o = 128; o > 0; o >>= 1) { if (tid < o) sh[tid] += sh[tid + o]; __syncthreads(); }
  double sum_s = sh[0]; __syncthreads();
  sh[tid] = st; __syncthreads();
  for (int o = 128; o > 0; o >>= 1) { if (tid < o) sh[tid] += sh[tid + o]; __syncthreads(); }
  double sum_t = sh[0]; __syncthreads();

  float mean_s = (float)(sum_s / NP);
  float mean_t = (float)(sum_t / NP);

  double acc = 0;
  for (int k = tid; k < NP; k += 256) {
    float pred = dtw[k] / mean_s;
    float targ = dtw[NP + k] / mean_t;
    float d = pred - targ;
    float ad = fabsf(d);
    float v = ad < 1.f ? 0.5f * d * d : ad - 0.5f;
    acc += (double)v;
  }
  sh[tid] = acc; __syncthreads();
  for (int o = 128; o > 0; o >>= 1) { if (tid < o) sh[tid] += sh[tid + o]; __syncthreads(); }
  if (tid == 0) out[0] = (float)(sh[0] / NP);
}

extern "C" void kernel_launch(void* const* d_in, const int* in_sizes, int n_in,
                              void* d_out, int out_size, void* d_ws, size_t ws_size,
                              hipStream_t stream) {
  const float* student = (const float*)d_in[0];
  const float* teacher = (const float*)d_in[1];
  const float* gamma   = (const float*)d_in[2];
  float* ws  = (float*)d_ws;
  float* dtw = ws;             // [2*NP]
  float* xnb = ws + 2 * NP;    // [2*BB*TT]

  xn_kernel<<<24, 256, 0, stream>>>(student, teacher, xnb);
  sdtw_kernel<<<dim3(NPAIR, 2), 256, 0, stream>>>(student, teacher, xnb, gamma, dtw);
  reduce_kernel<<<1, 256, 0, stream>>>(dtw, (float*)d_out);
}